// Round 15
// baseline (136.590 us; speedup 1.0000x reference)
//
#include <hip/hip_runtime.h>
#include <hip/hip_bf16.h>

// Causal self-attention forward, B=4 S=2048 H=16 D=64, fp32 in/out, bf16 MFMA.
// qkv: (B,S,3,H,D) f32.  out: (B,H,S,D) f32.
// Round 15: revert to R13 structure (best bench: paired chunks, K single-buf,
// 2 barriers/tile, 33.8KB LDS). Tweaks: PPIT 72->68 (lg-group bank shift 16->8,
// kills the 4-way P-write conflict -> 2-way free), setprio around QK^T too.

#define S_LEN 2048
#define NHEAD 16
#define DHEAD 64
#define CHUNK 64     // q rows per chunk; wave owns 16 rows of each of the 2 chunks
#define KVBLK 64
#define NQB   (S_LEN / CHUNK)   // 32
#define NPAIR (NQB / 2)         // 16
#define SROW  3072   // s-stride in floats = 3*NHEAD*DHEAD
#define KOFF  1024
#define VOFF  2048
#define PPIT  68     // P row pitch (shorts): 136 B rows; lg-group bank shift = 8

typedef __attribute__((ext_vector_type(8))) short bf16x8;
typedef __attribute__((ext_vector_type(4))) float f32x4;

__device__ __forceinline__ short f2bf(float f) {
    union { __hip_bfloat16 b; short s; } u;
    u.b = __float2bfloat16(f);
    return u.s;
}
__device__ __forceinline__ short f2bf_trunc(float f) {   // truncate: 1 VALU op
    union { float f; unsigned int u; } v;
    v.f = f;
    return (short)(v.u >> 16);
}
__device__ __forceinline__ unsigned int pack2(float lo, float hi) {
    return (unsigned int)(unsigned short)f2bf(lo) | ((unsigned int)(unsigned short)f2bf(hi) << 16);
}
__device__ __forceinline__ void gl_lds16(const short* g, short* l) {
    __builtin_amdgcn_global_load_lds(
        (const __attribute__((address_space(1))) void*)g,
        (__attribute__((address_space(3))) void*)l, 16, 0, 0);
}
__device__ __forceinline__ float fexp2(float x) {   // 2^x, single v_exp_f32
    float r;
    asm("v_exp_f32 %0, %1" : "=v"(r) : "v"(x));
    return r;
}

// ---------------- pre-pass: qkv f32 -> ws bf16 (K row-major, V transposed) ---
__global__ __launch_bounds__(256)
void prepass_kernel(const float* __restrict__ qkv,
                    short* __restrict__ kws, short* __restrict__ vtws)
{
    __shared__ float lds_t[64][65];

    const int tid = threadIdx.x;
    const int bh  = blockIdx.x >> 5;
    const int s0  = (blockIdx.x & 31) * 64;

    const float* qkv_bh = qkv + (size_t)(bh >> 4) * (S_LEN * SROW) + (bh & 15) * DHEAD;
    short* kws_bh = kws  + (size_t)bh * (S_LEN * DHEAD);
    short* vt_bh  = vtws + (size_t)bh * (S_LEN * DHEAD);

    const int row = tid >> 2;
    const int cq  = (tid & 3) * 16;

    {
        const float* kp = qkv_bh + (size_t)(s0 + row) * SROW + KOFF + cq;
        f32x4 a = *(const f32x4*)kp,       b = *(const f32x4*)(kp + 4);
        f32x4 c = *(const f32x4*)(kp + 8), d = *(const f32x4*)(kp + 12);
        bf16x8 w0, w1;
        #pragma unroll
        for (int j = 0; j < 4; ++j) {
            w0[j] = f2bf(a[j]); w0[4 + j] = f2bf(b[j]);
            w1[j] = f2bf(c[j]); w1[4 + j] = f2bf(d[j]);
        }
        *(bf16x8*)&kws_bh[(size_t)(s0 + row) * 64 + cq]     = w0;
        *(bf16x8*)&kws_bh[(size_t)(s0 + row) * 64 + cq + 8] = w1;
    }
    {
        const float* vp = qkv_bh + (size_t)(s0 + row) * SROW + VOFF + cq;
        f32x4 a = *(const f32x4*)vp,       b = *(const f32x4*)(vp + 4);
        f32x4 c = *(const f32x4*)(vp + 8), d = *(const f32x4*)(vp + 12);
        #pragma unroll
        for (int j = 0; j < 4; ++j) {
            lds_t[row][cq + j]      = a[j];
            lds_t[row][cq + 4 + j]  = b[j];
            lds_t[row][cq + 8 + j]  = c[j];
            lds_t[row][cq + 12 + j] = d[j];
        }
    }
    __syncthreads();
    {
        const int d = row, sq = cq;
        bf16x8 w0, w1;
        #pragma unroll
        for (int j = 0; j < 8; ++j) {
            w0[j] = f2bf(lds_t[sq + j][d]);
            w1[j] = f2bf(lds_t[sq + 8 + j][d]);
        }
        *(bf16x8*)&vt_bh[(size_t)d * S_LEN + s0 + sq]     = w0;
        *(bf16x8*)&vt_bh[(size_t)d * S_LEN + s0 + sq + 8] = w1;
    }
}

// ---------------- main kernel (verified layout, ~33.5 KB LDS) ----------------
__global__ __launch_bounds__(256)
void attn_fwd_ws(const float* __restrict__ qkv,
                 const short* __restrict__ kws, const short* __restrict__ vtws,
                 float* __restrict__ out)
{
    __shared__ __attribute__((aligned(16))) short lds_k [KVBLK * 64];     // 8 KB (single)
    __shared__ __attribute__((aligned(16))) short lds_vt[2][DHEAD * 64];  // 16 KB (dbuf)
    __shared__ __attribute__((aligned(16))) short lds_p [4][16][PPIT];    // 8.5 KB

    const int tid  = threadIdx.x;
    const int wave = tid >> 6;
    const int lane = tid & 63;
    const int l16  = lane & 15;
    const int lg   = lane >> 4;
    const int lr8  = lane >> 3;
    const int lc8  = lane & 7;
    const int swz  = (lc8 * 8) ^ (lr8 << 3);   // DMA-source swizzle (shorts)
    const int rsw  = (l16 & 7) << 3;           // K/V read-side swizzle base

    const int bid = blockIdx.x;
    const int pr  = bid & 15;
    const int bh  = bid >> 4;

    const float* qkv_bh = qkv + (size_t)(bh >> 4) * (S_LEN * SROW) + (bh & 15) * DHEAD;
    const short* kws_bh = kws  + (size_t)bh * (S_LEN * DHEAD);
    const short* vt_bh  = vtws + (size_t)bh * (S_LEN * DHEAD);

    const int qbA = pr;
    const int qbB = NQB - 1 - pr;
    const int qloA = qbA * CHUNK + wave * 16;
    const int qloB = qbB * CHUNK + wave * 16;

    // P bases: all P stores/loads are compile-time offsets from these
    short* pwr = &lds_p[wave][lg * 4][l16];        // writer: + r*PPIT + c*16
    const short* prd = &lds_p[wave][l16][lg * 8];  // reader: + ks*32

    // ---- prologue: DMA K(0) and V(0) ----
    {
        #pragma unroll
        for (int i = 0; i < 2; ++i) {
            const int row = i * 32 + wave * 8 + lr8;
            gl_lds16(&kws_bh[(size_t)row * 64 + swz],    &lds_k    [i * 2048 + wave * 512]);
            gl_lds16(&vt_bh [(size_t)row * S_LEN + swz], &lds_vt[0][i * 2048 + wave * 512]);
        }
    }

    // ---- Q fragments (pre-scaled by 0.125 * log2(e): logits in log2 domain) ----
    const float qscale = 0.125f * 1.44269504088896f;
    bf16x8 qf[2][2];
    #pragma unroll
    for (int m = 0; m < 2; ++m) {
        const int qrow = (m == 0 ? qloA : qloB) + l16;
        #pragma unroll
        for (int ks = 0; ks < 2; ++ks) {
            const float* qp = qkv_bh + (size_t)qrow * SROW + ks * 32 + lg * 8;
            f32x4 a = *(const f32x4*)qp;
            f32x4 c = *(const f32x4*)(qp + 4);
            bf16x8 v;
            #pragma unroll
            for (int j = 0; j < 4; ++j) { v[j] = f2bf(a[j] * qscale); v[4 + j] = f2bf(c[j] * qscale); }
            qf[m][ks] = v;
        }
    }

    // ---- ones B-fragment for row-sum MFMA ----
    bf16x8 onesf;
    #pragma unroll
    for (int j = 0; j < 8; ++j) onesf[j] = (short)0x3F80;   // bf16 1.0

    // ---- flash state (verified D layout: q = qlo_m + lg*4 + r) ----
    f32x4 o[2][4];        // o[m][n][r] = O[q][d = n*16 + l16]
    f32x4 lsum[2];        // lsum[m][r] = running sum of P over k for row q
    float m_r[2][4];      // running max (log2 domain)
    #pragma unroll
    for (int m = 0; m < 2; ++m) {
        #pragma unroll
        for (int n = 0; n < 4; ++n) o[m][n] = (f32x4){0.f, 0.f, 0.f, 0.f};
        lsum[m] = (f32x4){0.f, 0.f, 0.f, 0.f};
        #pragma unroll
        for (int r = 0; r < 4; ++r) m_r[m][r] = -1e30f;
    }

    __syncthreads();   // tile 0 resident

    const int ntiles = qbB + 1;
    int cur = 0;

    for (int it = 0; it < ntiles; ++it) {
        const int kv0 = it * KVBLK;
        const bool actA = (kv0 <= qloA + 15);

        // ---- S = Q K^T (K fully consumed here) ----
        f32x4 s[2][4];
        #pragma unroll
        for (int m = 0; m < 2; ++m)
            #pragma unroll
            for (int c = 0; c < 4; ++c) s[m][c] = (f32x4){0.f, 0.f, 0.f, 0.f};
        __builtin_amdgcn_s_setprio(1);
        #pragma unroll
        for (int ks = 0; ks < 2; ++ks) {
            #pragma unroll
            for (int c = 0; c < 4; ++c) {
                bf16x8 kf = *(const bf16x8*)&lds_k[(c * 16 + l16) * 64 + ((ks * 32 + lg * 8) ^ rsw)];
                s[1][c] = __builtin_amdgcn_mfma_f32_16x16x32_bf16(qf[1][ks], kf, s[1][c], 0, 0, 0);
                if (actA)
                    s[0][c] = __builtin_amdgcn_mfma_f32_16x16x32_bf16(qf[0][ks], kf, s[0][c], 0, 0, 0);
            }
        }
        __builtin_amdgcn_s_setprio(0);

        __syncthreads();   // K consumed by all waves -> safe to overwrite

        // ---- issue next tile's DMA (lands under softmax+PV) ----
        if (it + 1 < ntiles) {
            const int kn = kv0 + KVBLK;
            #pragma unroll
            for (int i = 0; i < 2; ++i) {
                const int row = i * 32 + wave * 8 + lr8;
                gl_lds16(&kws_bh[(size_t)(kn + row) * 64 + swz],  &lds_k          [i * 2048 + wave * 512]);
                gl_lds16(&vt_bh [(size_t)row * S_LEN + kn + swz], &lds_vt[cur ^ 1][i * 2048 + wave * 512]);
            }
        }

        // ---- per chunk (B first, then A): softmax -> P -> PV ----
        #pragma unroll
        for (int mi = 0; mi < 2; ++mi) {
            const int m = 1 - mi;
            if (m == 0 && !actA) continue;
            const int qlo_m = (m == 0) ? qloA : qloB;

            // causal mask (q = qlo_m + lg*4 + r, k = kv0 + c*16 + l16)
            if (kv0 + KVBLK - 1 > qlo_m) {
                #pragma unroll
                for (int r = 0; r < 4; ++r) {
                    const int qg = qlo_m + lg * 4 + r;
                    #pragma unroll
                    for (int c = 0; c < 4; ++c)
                        if (kv0 + c * 16 + l16 > qg) s[m][c][r] = -1e30f;
                }
            }

            // in-lane per-row max over c
            float lmax[4];
            #pragma unroll
            for (int r = 0; r < 4; ++r)
                lmax[r] = fmaxf(fmaxf(s[m][0][r], s[m][1][r]), fmaxf(s[m][2][r], s[m][3][r]));

            // defer-max vote (THR = 11.54 log2-units)
            const int okflag = (lmax[0] <= m_r[m][0] + 11.54f) && (lmax[1] <= m_r[m][1] + 11.54f) &&
                               (lmax[2] <= m_r[m][2] + 11.54f) && (lmax[3] <= m_r[m][3] + 11.54f);
            if (!__all(okflag)) {
                #pragma unroll
                for (int r = 0; r < 4; ++r) {
                    float mt = lmax[r];
                    mt = fmaxf(mt, __shfl_xor(mt, 1));
                    mt = fmaxf(mt, __shfl_xor(mt, 2));
                    mt = fmaxf(mt, __shfl_xor(mt, 4));
                    mt = fmaxf(mt, __shfl_xor(mt, 8));
                    const float mn    = fmaxf(m_r[m][r], mt);
                    const float alpha = fexp2(m_r[m][r] - mn);
                    m_r[m][r] = mn;
                    lsum[m][r] *= alpha;
                    #pragma unroll
                    for (int n = 0; n < 4; ++n) o[m][n][r] *= alpha;
                }
            }

            // P = 2^(S - m) -> identity-layout P rows (compile-time offsets)
            #pragma unroll
            for (int c = 0; c < 4; ++c) {
                #pragma unroll
                for (int r = 0; r < 4; ++r) {
                    const float p = fexp2(s[m][c][r] - m_r[m][r]);
                    pwr[r * PPIT + c * 16] = f2bf_trunc(p);
                }
            }
            // wave-local P visibility before cross-lane fragment reads
            asm volatile("s_waitcnt lgkmcnt(0)" ::: "memory");
            __builtin_amdgcn_sched_barrier(0);

            // ---- O += P V ; lsum += P · 1 ----
            __builtin_amdgcn_s_setprio(1);
            #pragma unroll
            for (int ks = 0; ks < 2; ++ks) {
                bf16x8 pa = *(const bf16x8*)&prd[ks * 32];
                lsum[m] = __builtin_amdgcn_mfma_f32_16x16x32_bf16(pa, onesf, lsum[m], 0, 0, 0);
                #pragma unroll
                for (int n = 0; n < 4; ++n) {
                    bf16x8 vf = *(const bf16x8*)&lds_vt[cur][(n * 16 + l16) * 64 + ((ks * 32 + lg * 8) ^ rsw)];
                    o[m][n] = __builtin_amdgcn_mfma_f32_16x16x32_bf16(pa, vf, o[m][n], 0, 0, 0);
                }
            }
            __builtin_amdgcn_s_setprio(0);
        }
        __syncthreads();   // drains K/V DMA; PV done before next V overwrite
        cur ^= 1;
    }

    // ---- epilogue (verified form): out[q][d] = o[m][n][r] / lsum[m][r] ----
    #pragma unroll
    for (int m = 0; m < 2; ++m) {
        const int qlo_m = (m == 0) ? qloA : qloB;
        float* outp = out + ((size_t)bh * S_LEN + qlo_m) * DHEAD;
        #pragma unroll
        for (int r = 0; r < 4; ++r) {
            const float inv = 1.0f / lsum[m][r];
            #pragma unroll
            for (int n = 0; n < 4; ++n)
                outp[(lg * 4 + r) * DHEAD + n * 16 + l16] = o[m][n][r] * inv;
        }
    }
}

// ---------------- fallback (round-2 kernel, verified) ------------------------
#define KP 72
#define VP 72
#define PP 76
__global__ __launch_bounds__(256)
void attn_fwd_fallback(const float* __restrict__ qkv, float* __restrict__ out)
{
    __shared__ __attribute__((aligned(16))) short lds_k [KVBLK * KP];
    __shared__ __attribute__((aligned(16))) short lds_vt[DHEAD * VP];
    __shared__ __attribute__((aligned(16))) short lds_p [4 * 32 * PP];

    const int tid  = threadIdx.x;
    const int wave = tid >> 6;
    const int lane = tid & 63;
    const int l16  = lane & 15;
    const int lg   = lane >> 4;

    const int bid = blockIdx.x;
    const int pr  = bid & 15;
    const int bh  = bid >> 4;

    const float* qkv_bh = qkv + (size_t)(bh >> 4) * (S_LEN * SROW) + (bh & 15) * DHEAD;
    const int qbA = pr;
    const int qbB = NQB - 1 - pr;
    const int qloA = qbA * CHUNK + wave * 16;
    const int qloB = qbB * CHUNK + wave * 16;

    bf16x8 qf[2][2];
    #pragma unroll
    for (int m = 0; m < 2; ++m) {
        const int qrow = (m == 0 ? qloA : qloB) + l16;
        #pragma unroll
        for (int ks = 0; ks < 2; ++ks) {
            const float* qp = qkv_bh + (size_t)qrow * SROW + ks * 32 + lg * 8;
            f32x4 a = *(const f32x4*)qp;
            f32x4 c = *(const f32x4*)(qp + 4);
            bf16x8 v;
            #pragma unroll
            for (int j = 0; j < 4; ++j) { v[j] = f2bf(a[j] * 0.125f); v[4 + j] = f2bf(c[j] * 0.125f); }
            qf[m][ks] = v;
        }
    }

    f32x4 o[2][4];
    float m_r[2][4], l_r[2][4];
    #pragma unroll
    for (int m = 0; m < 2; ++m)
        #pragma unroll
        for (int n = 0; n < 4; ++n) o[m][n] = (f32x4){0.f, 0.f, 0.f, 0.f};
    #pragma unroll
    for (int m = 0; m < 2; ++m)
        #pragma unroll
        for (int r = 0; r < 4; ++r) { m_r[m][r] = -1e30f; l_r[m][r] = 0.f; }

    const int st_kr = tid >> 2;
    const int st_kc = (tid & 3) * 16;
    const int st_vp = tid & 31;
    const int st_vd = (tid >> 5) * 8;

    f32x4 pk[4], pv[4];
    const int ntiles = qbB + 1;
    {
        const float* kp = qkv_bh + (size_t)st_kr * SROW + KOFF + st_kc;
        pk[0] = *(const f32x4*)kp;       pk[1] = *(const f32x4*)(kp + 4);
        pk[2] = *(const f32x4*)(kp + 8); pk[3] = *(const f32x4*)(kp + 12);
        const float* vp = qkv_bh + (size_t)(2 * st_vp) * SROW + VOFF + st_vd;
        pv[0] = *(const f32x4*)vp;           pv[1] = *(const f32x4*)(vp + 4);
        pv[2] = *(const f32x4*)(vp + SROW);  pv[3] = *(const f32x4*)(vp + SROW + 4);
    }

    for (int it = 0; it < ntiles; ++it) {
        const int kv0 = it * KVBLK;
        {
            bf16x8 w0, w1;
            #pragma unroll
            for (int j = 0; j < 4; ++j) {
                w0[j] = f2bf(pk[0][j]); w0[4 + j] = f2bf(pk[1][j]);
                w1[j] = f2bf(pk[2][j]); w1[4 + j] = f2bf(pk[3][j]);
            }
            *(bf16x8*)&lds_k[st_kr * KP + st_kc]     = w0;
            *(bf16x8*)&lds_k[st_kr * KP + st_kc + 8] = w1;
            #pragma unroll
            for (int i = 0; i < 4; ++i) {
                *(unsigned int*)&lds_vt[(st_vd + i)     * VP + 2 * st_vp] = pack2(pv[0][i], pv[2][i]);
                *(unsigned int*)&lds_vt[(st_vd + 4 + i) * VP + 2 * st_vp] = pack2(pv[1][i], pv[3][i]);
            }
        }
        __syncthreads();
        if (it + 1 < ntiles) {
            const int kn = kv0 + KVBLK;
            const float* kp = qkv_bh + (size_t)(kn + st_kr) * SROW + KOFF + st_kc;
            pk[0] = *(const f32x4*)kp;       pk[1] = *(const f32x4*)(kp + 4);
            pk[2] = *(const f32x4*)(kp + 8); pk[3] = *(const f32x4*)(kp + 12);
            const float* vp = qkv_bh + (size_t)(kn + 2 * st_vp) * SROW + VOFF + st_vd;
            pv[0] = *(const f32x4*)vp;           pv[1] = *(const f32x4*)(vp + 4);
            pv[2] = *(const f32x4*)(vp + SROW);  pv[3] = *(const f32x4*)(vp + SROW + 4);
        }
        const bool actA = (kv0 <= qloA + 15);
        f32x4 s[2][4];
        #pragma unroll
        for (int m = 0; m < 2; ++m)
            #pragma unroll
            for (int c = 0; c < 4; ++c) s[m][c] = (f32x4){0.f, 0.f, 0.f, 0.f};
        #pragma unroll
        for (int ks = 0; ks < 2; ++ks) {
            #pragma unroll
            for (int c = 0; c < 4; ++c) {
                bf16x8 kf = *(const bf16x8*)&lds_k[(c * 16 + l16) * KP + ks * 32 + lg * 8];
                s[1][c] = __builtin_amdgcn_mfma_f32_16x16x32_bf16(qf[1][ks], kf, s[1][c], 0, 0, 0);
                if (actA)
                    s[0][c] = __builtin_amdgcn_mfma_f32_16x16x32_bf16(qf[0][ks], kf, s[0][c], 0, 0, 0);
            }
        }
        short* pw = &lds_p[wave * 32 * PP];
        #pragma unroll
        for (int m = 0; m < 2; ++m) {
            if (m == 0 && !actA) continue;
            const int qlo_m = (m == 0) ? qloA : qloB;
            if (kv0 + KVBLK - 1 > qlo_m) {
                #pragma unroll
                for (int r = 0; r < 4; ++r) {
                    const int qg = qlo_m + lg * 4 + r;
                    #pragma unroll
                    for (int c = 0; c < 4; ++c)
                        if (kv0 + c * 16 + l16 > qg) s[m][c][r] = -1e30f;
                }
            }
            #pragma unroll
            for (int r = 0; r < 4; ++r) {
                float mt = fmaxf(fmaxf(s[m][0][r], s[m][1][r]), fmaxf(s[m][2][r], s[m][3][r]));
                mt = fmaxf(mt, __shfl_xor(mt, 1));
                mt = fmaxf(mt, __shfl_xor(mt, 2));
                mt = fmaxf(mt, __shfl_xor(mt, 4));
                mt = fmaxf(mt, __shfl_xor(mt, 8));
                const float mn    = fmaxf(m_r[m][r], mt);
                const float alpha = __expf(m_r[m][r] - mn);
                m_r[m][r] = mn;
                float p0 = __expf(s[m][0][r] - mn);
                float p1 = __expf(s[m][1][r] - mn);
                float p2 = __expf(s[m][2][r] - mn);
                float p3 = __expf(s[m][3][r] - mn);
                float rs = (p0 + p1) + (p2 + p3);
                rs += __shfl_xor(rs, 1);
                rs += __shfl_xor(rs, 2);
                rs += __shfl_xor(rs, 4);
                rs += __shfl_xor(rs, 8);
                l_r[m][r] = l_r[m][r] * alpha + rs;
                #pragma unroll
                for (int n = 0; n < 4; ++n) o[m][n][r] *= alpha;
                const int prow = m * 16 + lg * 4 + r;
                pw[prow * PP +      l16] = f2bf(p0);
                pw[prow * PP + 16 + l16] = f2bf(p1);
                pw[prow * PP + 32 + l16] = f2bf(p2);
                pw[prow * PP + 48 + l16] = f2bf(p3);
            }
        }
        asm volatile("s_waitcnt lgkmcnt(0)" ::: "memory");
        __builtin_amdgcn_sched_barrier(0);
        #pragma unroll
        for (int ks = 0; ks < 2; ++ks) {
            bf16x8 pa1 = *(const bf16x8*)&pw[(16 + l16) * PP + ks * 32 + lg * 8];
            #pragma unroll
            for (int n = 0; n < 4; ++n) {
                bf16x8 vf = *(const bf16x8*)&lds_vt[(n * 16 + l16) * VP + ks * 32 + lg * 8];
                o[1][n] = __builtin_amdgcn_mfma_f32_16x16x32_bf16(pa1, vf, o[1][n], 0, 0, 0);
            }
            if (actA) {
                bf16x8 pa0 = *(const bf16x8*)&pw[l16 * PP + ks * 32 + lg * 8];
                #pragma unroll
                for (int n = 0; n < 4; ++n) {
                    bf16x8 vf = *(const bf16x8*)&lds_vt[(n * 16 + l16) * VP + ks * 32 + lg * 8];
                    o[0][n] = __builtin_amdgcn_mfma_f32_16x16x32_bf16(pa0, vf, o[0][n], 0, 0, 0);
                }
            }
        }
        __syncthreads();
    }
    #pragma unroll
    for (int m = 0; m < 2; ++m) {
        const int qlo_m = (m == 0) ? qloA : qloB;
        float* outp = out + ((size_t)bh * S_LEN + qlo_m) * DHEAD;
        #pragma unroll
        for (int r = 0; r < 4; ++r) {
            const float inv = 1.0f / l_r[m][r];
            #pragma unroll
            for (int n = 0; n < 4; ++n)
                outp[(lg * 4 + r) * DHEAD + n * 16 + l16] = o[m][n][r] * inv;
        }
    }
}

extern "C" void kernel_launch(void* const* d_in, const int* in_sizes, int n_in,
                              void* d_out, int out_size, void* d_ws, size_t ws_size,
                              hipStream_t stream) {
    const float* qkv = (const float*)d_in[0];
    float* out = (float*)d_out;
    const size_t need = (size_t)2 * 64 * S_LEN * DHEAD * sizeof(short);  // 33.55 MB
    const int nblocks = NPAIR * 4 * NHEAD;   // 1024
    if (ws_size >= need) {
        short* kws  = (short*)d_ws;
        short* vtws = kws + (size_t)64 * S_LEN * DHEAD;
        prepass_kernel<<<dim3(64 * 32), dim3(256), 0, stream>>>(qkv, kws, vtws);
        attn_fwd_ws<<<dim3(nblocks), dim3(256), 0, stream>>>(qkv, kws, vtws, out);
    } else {
        attn_fwd_fallback<<<dim3(nblocks), dim3(256), 0, stream>>>(qkv, out);
    }
}

// Round 16
// 116.515 us; speedup vs baseline: 1.1723x; 1.1723x over previous
//
#include <hip/hip_runtime.h>
#include <hip/hip_bf16.h>

// Causal self-attention forward, B=4 S=2048 H=16 D=64, fp32 in/out, bf16 MFMA.
// qkv: (B,S,3,H,D) f32.  out: (B,H,S,D) f32.
// Round 16: exact revert to the round-13 artifact (measured best, 116.6 us).
// R15's changes both hurt: setprio around QK^T starved the softmax critical
// path (VALUBusy 39.7->34.3, dur +19us); the PPIT=68 conflict fix removed
// conflicts that were not on the critical path. R13 config: paired chunks,
// K single-buffered, 2 barriers/tile, exp2 domain, trunc-P, identity P
// pitch 72, setprio on PV only.

#define S_LEN 2048
#define NHEAD 16
#define DHEAD 64
#define CHUNK 64     // q rows per chunk; wave owns 16 rows of each of the 2 chunks
#define KVBLK 64
#define NQB   (S_LEN / CHUNK)   // 32
#define NPAIR (NQB / 2)         // 16
#define SROW  3072   // s-stride in floats = 3*NHEAD*DHEAD
#define KOFF  1024
#define VOFF  2048
#define PPIT  72     // P row pitch (shorts): 144 B rows

typedef __attribute__((ext_vector_type(8))) short bf16x8;
typedef __attribute__((ext_vector_type(4))) float f32x4;

__device__ __forceinline__ short f2bf(float f) {
    union { __hip_bfloat16 b; short s; } u;
    u.b = __float2bfloat16(f);
    return u.s;
}
__device__ __forceinline__ short f2bf_trunc(float f) {   // truncate: 1 VALU op
    union { float f; unsigned int u; } v;
    v.f = f;
    return (short)(v.u >> 16);
}
__device__ __forceinline__ unsigned int pack2(float lo, float hi) {
    return (unsigned int)(unsigned short)f2bf(lo) | ((unsigned int)(unsigned short)f2bf(hi) << 16);
}
__device__ __forceinline__ void gl_lds16(const short* g, short* l) {
    __builtin_amdgcn_global_load_lds(
        (const __attribute__((address_space(1))) void*)g,
        (__attribute__((address_space(3))) void*)l, 16, 0, 0);
}
__device__ __forceinline__ float fexp2(float x) {   // 2^x, single v_exp_f32
    float r;
    asm("v_exp_f32 %0, %1" : "=v"(r) : "v"(x));
    return r;
}

// ---------------- pre-pass: qkv f32 -> ws bf16 (K row-major, V transposed) ---
__global__ __launch_bounds__(256)
void prepass_kernel(const float* __restrict__ qkv,
                    short* __restrict__ kws, short* __restrict__ vtws)
{
    __shared__ float lds_t[64][65];

    const int tid = threadIdx.x;
    const int bh  = blockIdx.x >> 5;
    const int s0  = (blockIdx.x & 31) * 64;

    const float* qkv_bh = qkv + (size_t)(bh >> 4) * (S_LEN * SROW) + (bh & 15) * DHEAD;
    short* kws_bh = kws  + (size_t)bh * (S_LEN * DHEAD);
    short* vt_bh  = vtws + (size_t)bh * (S_LEN * DHEAD);

    const int row = tid >> 2;
    const int cq  = (tid & 3) * 16;

    {
        const float* kp = qkv_bh + (size_t)(s0 + row) * SROW + KOFF + cq;
        f32x4 a = *(const f32x4*)kp,       b = *(const f32x4*)(kp + 4);
        f32x4 c = *(const f32x4*)(kp + 8), d = *(const f32x4*)(kp + 12);
        bf16x8 w0, w1;
        #pragma unroll
        for (int j = 0; j < 4; ++j) {
            w0[j] = f2bf(a[j]); w0[4 + j] = f2bf(b[j]);
            w1[j] = f2bf(c[j]); w1[4 + j] = f2bf(d[j]);
        }
        *(bf16x8*)&kws_bh[(size_t)(s0 + row) * 64 + cq]     = w0;
        *(bf16x8*)&kws_bh[(size_t)(s0 + row) * 64 + cq + 8] = w1;
    }
    {
        const float* vp = qkv_bh + (size_t)(s0 + row) * SROW + VOFF + cq;
        f32x4 a = *(const f32x4*)vp,       b = *(const f32x4*)(vp + 4);
        f32x4 c = *(const f32x4*)(vp + 8), d = *(const f32x4*)(vp + 12);
        #pragma unroll
        for (int j = 0; j < 4; ++j) {
            lds_t[row][cq + j]      = a[j];
            lds_t[row][cq + 4 + j]  = b[j];
            lds_t[row][cq + 8 + j]  = c[j];
            lds_t[row][cq + 12 + j] = d[j];
        }
    }
    __syncthreads();
    {
        const int d = row, sq = cq;
        bf16x8 w0, w1;
        #pragma unroll
        for (int j = 0; j < 8; ++j) {
            w0[j] = f2bf(lds_t[sq + j][d]);
            w1[j] = f2bf(lds_t[sq + 8 + j][d]);
        }
        *(bf16x8*)&vt_bh[(size_t)d * S_LEN + s0 + sq]     = w0;
        *(bf16x8*)&vt_bh[(size_t)d * S_LEN + s0 + sq + 8] = w1;
    }
}

// ---------------- main kernel (verified layout, ~33 KB LDS) ------------------
__global__ __launch_bounds__(256)
void attn_fwd_ws(const float* __restrict__ qkv,
                 const short* __restrict__ kws, const short* __restrict__ vtws,
                 float* __restrict__ out)
{
    __shared__ __attribute__((aligned(16))) short lds_k [KVBLK * 64];     // 8 KB (single)
    __shared__ __attribute__((aligned(16))) short lds_vt[2][DHEAD * 64];  // 16 KB (dbuf)
    __shared__ __attribute__((aligned(16))) short lds_p [4][16][PPIT];    // 9 KB (identity+pad)

    const int tid  = threadIdx.x;
    const int wave = tid >> 6;
    const int lane = tid & 63;
    const int l16  = lane & 15;
    const int lg   = lane >> 4;
    const int lr8  = lane >> 3;
    const int lc8  = lane & 7;
    const int swz  = (lc8 * 8) ^ (lr8 << 3);   // DMA-source swizzle (shorts)
    const int rsw  = (l16 & 7) << 3;           // K/V read-side swizzle base

    const int bid = blockIdx.x;
    const int pr  = bid & 15;
    const int bh  = bid >> 4;

    const float* qkv_bh = qkv + (size_t)(bh >> 4) * (S_LEN * SROW) + (bh & 15) * DHEAD;
    const short* kws_bh = kws  + (size_t)bh * (S_LEN * DHEAD);
    const short* vt_bh  = vtws + (size_t)bh * (S_LEN * DHEAD);

    const int qbA = pr;
    const int qbB = NQB - 1 - pr;
    const int qloA = qbA * CHUNK + wave * 16;
    const int qloB = qbB * CHUNK + wave * 16;

    // P bases: all P stores/loads are compile-time offsets from these
    short* pwr = &lds_p[wave][lg * 4][l16];        // writer: + r*PPIT + c*16
    const short* prd = &lds_p[wave][l16][lg * 8];  // reader: + ks*32

    // ---- prologue: DMA K(0) and V(0) ----
    {
        #pragma unroll
        for (int i = 0; i < 2; ++i) {
            const int row = i * 32 + wave * 8 + lr8;
            gl_lds16(&kws_bh[(size_t)row * 64 + swz],    &lds_k    [i * 2048 + wave * 512]);
            gl_lds16(&vt_bh [(size_t)row * S_LEN + swz], &lds_vt[0][i * 2048 + wave * 512]);
        }
    }

    // ---- Q fragments (pre-scaled by 0.125 * log2(e): logits in log2 domain) ----
    const float qscale = 0.125f * 1.44269504088896f;
    bf16x8 qf[2][2];
    #pragma unroll
    for (int m = 0; m < 2; ++m) {
        const int qrow = (m == 0 ? qloA : qloB) + l16;
        #pragma unroll
        for (int ks = 0; ks < 2; ++ks) {
            const float* qp = qkv_bh + (size_t)qrow * SROW + ks * 32 + lg * 8;
            f32x4 a = *(const f32x4*)qp;
            f32x4 c = *(const f32x4*)(qp + 4);
            bf16x8 v;
            #pragma unroll
            for (int j = 0; j < 4; ++j) { v[j] = f2bf(a[j] * qscale); v[4 + j] = f2bf(c[j] * qscale); }
            qf[m][ks] = v;
        }
    }

    // ---- ones B-fragment for row-sum MFMA ----
    bf16x8 onesf;
    #pragma unroll
    for (int j = 0; j < 8; ++j) onesf[j] = (short)0x3F80;   // bf16 1.0

    // ---- flash state (verified D layout: q = qlo_m + lg*4 + r) ----
    f32x4 o[2][4];        // o[m][n][r] = O[q][d = n*16 + l16]
    f32x4 lsum[2];        // lsum[m][r] = running sum of P over k for row q
    float m_r[2][4];      // running max (log2 domain)
    #pragma unroll
    for (int m = 0; m < 2; ++m) {
        #pragma unroll
        for (int n = 0; n < 4; ++n) o[m][n] = (f32x4){0.f, 0.f, 0.f, 0.f};
        lsum[m] = (f32x4){0.f, 0.f, 0.f, 0.f};
        #pragma unroll
        for (int r = 0; r < 4; ++r) m_r[m][r] = -1e30f;
    }

    __syncthreads();   // tile 0 resident

    const int ntiles = qbB + 1;
    int cur = 0;

    for (int it = 0; it < ntiles; ++it) {
        const int kv0 = it * KVBLK;
        const bool actA = (kv0 <= qloA + 15);

        // ---- S = Q K^T (K fully consumed here) ----
        f32x4 s[2][4];
        #pragma unroll
        for (int m = 0; m < 2; ++m)
            #pragma unroll
            for (int c = 0; c < 4; ++c) s[m][c] = (f32x4){0.f, 0.f, 0.f, 0.f};
        #pragma unroll
        for (int ks = 0; ks < 2; ++ks) {
            #pragma unroll
            for (int c = 0; c < 4; ++c) {
                bf16x8 kf = *(const bf16x8*)&lds_k[(c * 16 + l16) * 64 + ((ks * 32 + lg * 8) ^ rsw)];
                s[1][c] = __builtin_amdgcn_mfma_f32_16x16x32_bf16(qf[1][ks], kf, s[1][c], 0, 0, 0);
                if (actA)
                    s[0][c] = __builtin_amdgcn_mfma_f32_16x16x32_bf16(qf[0][ks], kf, s[0][c], 0, 0, 0);
            }
        }

        __syncthreads();   // K consumed by all waves -> safe to overwrite

        // ---- issue next tile's DMA (lands under softmax+PV) ----
        if (it + 1 < ntiles) {
            const int kn = kv0 + KVBLK;
            #pragma unroll
            for (int i = 0; i < 2; ++i) {
                const int row = i * 32 + wave * 8 + lr8;
                gl_lds16(&kws_bh[(size_t)(kn + row) * 64 + swz],  &lds_k          [i * 2048 + wave * 512]);
                gl_lds16(&vt_bh [(size_t)row * S_LEN + kn + swz], &lds_vt[cur ^ 1][i * 2048 + wave * 512]);
            }
        }

        // ---- per chunk (B first, then A): softmax -> P -> PV ----
        #pragma unroll
        for (int mi = 0; mi < 2; ++mi) {
            const int m = 1 - mi;
            if (m == 0 && !actA) continue;
            const int qlo_m = (m == 0) ? qloA : qloB;

            // causal mask (q = qlo_m + lg*4 + r, k = kv0 + c*16 + l16)
            if (kv0 + KVBLK - 1 > qlo_m) {
                #pragma unroll
                for (int r = 0; r < 4; ++r) {
                    const int qg = qlo_m + lg * 4 + r;
                    #pragma unroll
                    for (int c = 0; c < 4; ++c)
                        if (kv0 + c * 16 + l16 > qg) s[m][c][r] = -1e30f;
                }
            }

            // in-lane per-row max over c
            float lmax[4];
            #pragma unroll
            for (int r = 0; r < 4; ++r)
                lmax[r] = fmaxf(fmaxf(s[m][0][r], s[m][1][r]), fmaxf(s[m][2][r], s[m][3][r]));

            // defer-max vote (THR = 11.54 log2-units == R9's 8 nat-units)
            const int okflag = (lmax[0] <= m_r[m][0] + 11.54f) && (lmax[1] <= m_r[m][1] + 11.54f) &&
                               (lmax[2] <= m_r[m][2] + 11.54f) && (lmax[3] <= m_r[m][3] + 11.54f);
            if (!__all(okflag)) {
                #pragma unroll
                for (int r = 0; r < 4; ++r) {
                    float mt = lmax[r];
                    mt = fmaxf(mt, __shfl_xor(mt, 1));
                    mt = fmaxf(mt, __shfl_xor(mt, 2));
                    mt = fmaxf(mt, __shfl_xor(mt, 4));
                    mt = fmaxf(mt, __shfl_xor(mt, 8));
                    const float mn    = fmaxf(m_r[m][r], mt);
                    const float alpha = fexp2(m_r[m][r] - mn);
                    m_r[m][r] = mn;
                    lsum[m][r] *= alpha;
                    #pragma unroll
                    for (int n = 0; n < 4; ++n) o[m][n][r] *= alpha;
                }
            }

            // P = 2^(S - m) -> identity-layout P rows (compile-time offsets)
            #pragma unroll
            for (int c = 0; c < 4; ++c) {
                #pragma unroll
                for (int r = 0; r < 4; ++r) {
                    const float p = fexp2(s[m][c][r] - m_r[m][r]);
                    pwr[r * PPIT + c * 16] = f2bf_trunc(p);
                }
            }
            // wave-local P visibility before cross-lane fragment reads
            asm volatile("s_waitcnt lgkmcnt(0)" ::: "memory");
            __builtin_amdgcn_sched_barrier(0);

            // ---- O += P V ; lsum += P · 1 ----
            __builtin_amdgcn_s_setprio(1);
            #pragma unroll
            for (int ks = 0; ks < 2; ++ks) {
                bf16x8 pa = *(const bf16x8*)&prd[ks * 32];
                lsum[m] = __builtin_amdgcn_mfma_f32_16x16x32_bf16(pa, onesf, lsum[m], 0, 0, 0);
                #pragma unroll
                for (int n = 0; n < 4; ++n) {
                    bf16x8 vf = *(const bf16x8*)&lds_vt[cur][(n * 16 + l16) * 64 + ((ks * 32 + lg * 8) ^ rsw)];
                    o[m][n] = __builtin_amdgcn_mfma_f32_16x16x32_bf16(pa, vf, o[m][n], 0, 0, 0);
                }
            }
            __builtin_amdgcn_s_setprio(0);
        }
        __syncthreads();   // drains K/V DMA; PV done before next V overwrite
        cur ^= 1;
    }

    // ---- epilogue (verified form): out[q][d] = o[m][n][r] / lsum[m][r] ----
    #pragma unroll
    for (int m = 0; m < 2; ++m) {
        const int qlo_m = (m == 0) ? qloA : qloB;
        float* outp = out + ((size_t)bh * S_LEN + qlo_m) * DHEAD;
        #pragma unroll
        for (int r = 0; r < 4; ++r) {
            const float inv = 1.0f / lsum[m][r];
            #pragma unroll
            for (int n = 0; n < 4; ++n)
                outp[(lg * 4 + r) * DHEAD + n * 16 + l16] = o[m][n][r] * inv;
        }
    }
}

// ---------------- fallback (round-2 kernel, verified) ------------------------
#define KP 72
#define VP 72
#define PP 76
__global__ __launch_bounds__(256)
void attn_fwd_fallback(const float* __restrict__ qkv, float* __restrict__ out)
{
    __shared__ __attribute__((aligned(16))) short lds_k [KVBLK * KP];
    __shared__ __attribute__((aligned(16))) short lds_vt[DHEAD * VP];
    __shared__ __attribute__((aligned(16))) short lds_p [4 * 32 * PP];

    const int tid  = threadIdx.x;
    const int wave = tid >> 6;
    const int lane = tid & 63;
    const int l16  = lane & 15;
    const int lg   = lane >> 4;

    const int bid = blockIdx.x;
    const int pr  = bid & 15;
    const int bh  = bid >> 4;

    const float* qkv_bh = qkv + (size_t)(bh >> 4) * (S_LEN * SROW) + (bh & 15) * DHEAD;
    const int qbA = pr;
    const int qbB = NQB - 1 - pr;
    const int qloA = qbA * CHUNK + wave * 16;
    const int qloB = qbB * CHUNK + wave * 16;

    bf16x8 qf[2][2];
    #pragma unroll
    for (int m = 0; m < 2; ++m) {
        const int qrow = (m == 0 ? qloA : qloB) + l16;
        #pragma unroll
        for (int ks = 0; ks < 2; ++ks) {
            const float* qp = qkv_bh + (size_t)qrow * SROW + ks * 32 + lg * 8;
            f32x4 a = *(const f32x4*)qp;
            f32x4 c = *(const f32x4*)(qp + 4);
            bf16x8 v;
            #pragma unroll
            for (int j = 0; j < 4; ++j) { v[j] = f2bf(a[j] * 0.125f); v[4 + j] = f2bf(c[j] * 0.125f); }
            qf[m][ks] = v;
        }
    }

    f32x4 o[2][4];
    float m_r[2][4], l_r[2][4];
    #pragma unroll
    for (int m = 0; m < 2; ++m)
        #pragma unroll
        for (int n = 0; n < 4; ++n) o[m][n] = (f32x4){0.f, 0.f, 0.f, 0.f};
    #pragma unroll
    for (int m = 0; m < 2; ++m)
        #pragma unroll
        for (int r = 0; r < 4; ++r) { m_r[m][r] = -1e30f; l_r[m][r] = 0.f; }

    const int st_kr = tid >> 2;
    const int st_kc = (tid & 3) * 16;
    const int st_vp = tid & 31;
    const int st_vd = (tid >> 5) * 8;

    f32x4 pk[4], pv[4];
    const int ntiles = qbB + 1;
    {
        const float* kp = qkv_bh + (size_t)st_kr * SROW + KOFF + st_kc;
        pk[0] = *(const f32x4*)kp;       pk[1] = *(const f32x4*)(kp + 4);
        pk[2] = *(const f32x4*)(kp + 8); pk[3] = *(const f32x4*)(kp + 12);
        const float* vp = qkv_bh + (size_t)(2 * st_vp) * SROW + VOFF + st_vd;
        pv[0] = *(const f32x4*)vp;           pv[1] = *(const f32x4*)(vp + 4);
        pv[2] = *(const f32x4*)(vp + SROW);  pv[3] = *(const f32x4*)(vp + SROW + 4);
    }

    for (int it = 0; it < ntiles; ++it) {
        const int kv0 = it * KVBLK;
        {
            bf16x8 w0, w1;
            #pragma unroll
            for (int j = 0; j < 4; ++j) {
                w0[j] = f2bf(pk[0][j]); w0[4 + j] = f2bf(pk[1][j]);
                w1[j] = f2bf(pk[2][j]); w1[4 + j] = f2bf(pk[3][j]);
            }
            *(bf16x8*)&lds_k[st_kr * KP + st_kc]     = w0;
            *(bf16x8*)&lds_k[st_kr * KP + st_kc + 8] = w1;
            #pragma unroll
            for (int i = 0; i < 4; ++i) {
                *(unsigned int*)&lds_vt[(st_vd + i)     * VP + 2 * st_vp] = pack2(pv[0][i], pv[2][i]);
                *(unsigned int*)&lds_vt[(st_vd + 4 + i) * VP + 2 * st_vp] = pack2(pv[1][i], pv[3][i]);
            }
        }
        __syncthreads();
        if (it + 1 < ntiles) {
            const int kn = kv0 + KVBLK;
            const float* kp = qkv_bh + (size_t)(kn + st_kr) * SROW + KOFF + st_kc;
            pk[0] = *(const f32x4*)kp;       pk[1] = *(const f32x4*)(kp + 4);
            pk[2] = *(const f32x4*)(kp + 8); pk[3] = *(const f32x4*)(kp + 12);
            const float* vp = qkv_bh + (size_t)(kn + 2 * st_vp) * SROW + VOFF + st_vd;
            pv[0] = *(const f32x4*)vp;           pv[1] = *(const f32x4*)(vp + 4);
            pv[2] = *(const f32x4*)(vp + SROW);  pv[3] = *(const f32x4*)(vp + SROW + 4);
        }
        const bool actA = (kv0 <= qloA + 15);
        f32x4 s[2][4];
        #pragma unroll
        for (int m = 0; m < 2; ++m)
            #pragma unroll
            for (int c = 0; c < 4; ++c) s[m][c] = (f32x4){0.f, 0.f, 0.f, 0.f};
        #pragma unroll
        for (int ks = 0; ks < 2; ++ks) {
            #pragma unroll
            for (int c = 0; c < 4; ++c) {
                bf16x8 kf = *(const bf16x8*)&lds_k[(c * 16 + l16) * KP + ks * 32 + lg * 8];
                s[1][c] = __builtin_amdgcn_mfma_f32_16x16x32_bf16(qf[1][ks], kf, s[1][c], 0, 0, 0);
                if (actA)
                    s[0][c] = __builtin_amdgcn_mfma_f32_16x16x32_bf16(qf[0][ks], kf, s[0][c], 0, 0, 0);
            }
        }
        short* pw = &lds_p[wave * 32 * PP];
        #pragma unroll
        for (int m = 0; m < 2; ++m) {
            if (m == 0 && !actA) continue;
            const int qlo_m = (m == 0) ? qloA : qloB;
            if (kv0 + KVBLK - 1 > qlo_m) {
                #pragma unroll
                for (int r = 0; r < 4; ++r) {
                    const int qg = qlo_m + lg * 4 + r;
                    #pragma unroll
                    for (int c = 0; c < 4; ++c)
                        if (kv0 + c * 16 + l16 > qg) s[m][c][r] = -1e30f;
                }
            }
            #pragma unroll
            for (int r = 0; r < 4; ++r) {
                float mt = fmaxf(fmaxf(s[m][0][r], s[m][1][r]), fmaxf(s[m][2][r], s[m][3][r]));
                mt = fmaxf(mt, __shfl_xor(mt, 1));
                mt = fmaxf(mt, __shfl_xor(mt, 2));
                mt = fmaxf(mt, __shfl_xor(mt, 4));
                mt = fmaxf(mt, __shfl_xor(mt, 8));
                const float mn    = fmaxf(m_r[m][r], mt);
                const float alpha = __expf(m_r[m][r] - mn);
                m_r[m][r] = mn;
                float p0 = __expf(s[m][0][r] - mn);
                float p1 = __expf(s[m][1][r] - mn);
                float p2 = __expf(s[m][2][r] - mn);
                float p3 = __expf(s[m][3][r] - mn);
                float rs = (p0 + p1) + (p2 + p3);
                rs += __shfl_xor(rs, 1);
                rs += __shfl_xor(rs, 2);
                rs += __shfl_xor(rs, 4);
                rs += __shfl_xor(rs, 8);
                l_r[m][r] = l_r[m][r] * alpha + rs;
                #pragma unroll
                for (int n = 0; n < 4; ++n) o[m][n][r] *= alpha;
                const int prow = m * 16 + lg * 4 + r;
                pw[prow * PP +      l16] = f2bf(p0);
                pw[prow * PP + 16 + l16] = f2bf(p1);
                pw[prow * PP + 32 + l16] = f2bf(p2);
                pw[prow * PP + 48 + l16] = f2bf(p3);
            }
        }
        asm volatile("s_waitcnt lgkmcnt(0)" ::: "memory");
        __builtin_amdgcn_sched_barrier(0);
        #pragma unroll
        for (int ks = 0; ks < 2; ++ks) {
            bf16x8 pa1 = *(const bf16x8*)&pw[(16 + l16) * PP + ks * 32 + lg * 8];
            #pragma unroll
            for (int n = 0; n < 4; ++n) {
                bf16x8 vf = *(const bf16x8*)&lds_vt[(n * 16 + l16) * VP + ks * 32 + lg * 8];
                o[1][n] = __builtin_amdgcn_mfma_f32_16x16x32_bf16(pa1, vf, o[1][n], 0, 0, 0);
            }
            if (actA) {
                bf16x8 pa0 = *(const bf16x8*)&pw[l16 * PP + ks * 32 + lg * 8];
                #pragma unroll
                for (int n = 0; n < 4; ++n) {
                    bf16x8 vf = *(const bf16x8*)&lds_vt[(n * 16 + l16) * VP + ks * 32 + lg * 8];
                    o[0][n] = __builtin_amdgcn_mfma_f32_16x16x32_bf16(pa0, vf, o[0][n], 0, 0, 0);
                }
            }
        }
        __syncthreads();
    }
    #pragma unroll
    for (int m = 0; m < 2; ++m) {
        const int qlo_m = (m == 0) ? qloA : qloB;
        float* outp = out + ((size_t)bh * S_LEN + qlo_m) * DHEAD;
        #pragma unroll
        for (int r = 0; r < 4; ++r) {
            const float inv = 1.0f / l_r[m][r];
            #pragma unroll
            for (int n = 0; n < 4; ++n)
                outp[(lg * 4 + r) * DHEAD + n * 16 + l16] = o[m][n][r] * inv;
        }
    }
}

extern "C" void kernel_launch(void* const* d_in, const int* in_sizes, int n_in,
                              void* d_out, int out_size, void* d_ws, size_t ws_size,
                              hipStream_t stream) {
    const float* qkv = (const float*)d_in[0];
    float* out = (float*)d_out;
    const size_t need = (size_t)2 * 64 * S_LEN * DHEAD * sizeof(short);  // 33.55 MB
    const int nblocks = NPAIR * 4 * NHEAD;   // 1024
    if (ws_size >= need) {
        short* kws  = (short*)d_ws;
        short* vtws = kws + (size_t)64 * S_LEN * DHEAD;
        prepass_kernel<<<dim3(64 * 32), dim3(256), 0, stream>>>(qkv, kws, vtws);
        attn_fwd_ws<<<dim3(nblocks), dim3(256), 0, stream>>>(qkv, kws, vtws, out);
    } else {
        attn_fwd_fallback<<<dim3(nblocks), dim3(256), 0, stream>>>(qkv, out);
    }
}

// Round 17
// 96.088 us; speedup vs baseline: 1.4215x; 1.2126x over previous
//
#include <hip/hip_runtime.h>
#include <hip/hip_bf16.h>

// Causal self-attention forward, B=4 S=2048 H=16 D=64, fp32 in/out, bf16 MFMA.
// qkv: (B,S,3,H,D) f32.  out: (B,H,S,D) f32.
// Round 17: chunk-per-wave 8-wave blocks (512 thr). Waves 0-3 own chunk pr's
// four 16-row slices; waves 4-7 own chunk 31-pr's. Same KV staging volume as
// R13 (one pass per pair-block) but per-wave serial chain halves (one chunk:
// 8 QK^T + 10 PV MFMA + one softmax chain) and per-wave state halves
// (R14 measured 72 VGPR for this body) -> up to 24 resident waves/CU.
// Per-chunk math = R13's verified body (exp2, trunc-P, PPIT 72, PV setprio).

#define S_LEN 2048
#define NHEAD 16
#define DHEAD 64
#define CHUNK 64     // q rows per chunk; each wave owns 16 rows of ONE chunk
#define KVBLK 64
#define NQB   (S_LEN / CHUNK)   // 32
#define NPAIR (NQB / 2)         // 16
#define SROW  3072   // s-stride in floats = 3*NHEAD*DHEAD
#define KOFF  1024
#define VOFF  2048
#define PPIT  72     // P row pitch (shorts)

typedef __attribute__((ext_vector_type(8))) short bf16x8;
typedef __attribute__((ext_vector_type(4))) float f32x4;

__device__ __forceinline__ short f2bf(float f) {
    union { __hip_bfloat16 b; short s; } u;
    u.b = __float2bfloat16(f);
    return u.s;
}
__device__ __forceinline__ short f2bf_trunc(float f) {   // truncate: 1 VALU op
    union { float f; unsigned int u; } v;
    v.f = f;
    return (short)(v.u >> 16);
}
__device__ __forceinline__ unsigned int pack2(float lo, float hi) {
    return (unsigned int)(unsigned short)f2bf(lo) | ((unsigned int)(unsigned short)f2bf(hi) << 16);
}
__device__ __forceinline__ void gl_lds16(const short* g, short* l) {
    __builtin_amdgcn_global_load_lds(
        (const __attribute__((address_space(1))) void*)g,
        (__attribute__((address_space(3))) void*)l, 16, 0, 0);
}
__device__ __forceinline__ float fexp2(float x) {   // 2^x, single v_exp_f32
    float r;
    asm("v_exp_f32 %0, %1" : "=v"(r) : "v"(x));
    return r;
}

// ---------------- pre-pass: qkv f32 -> ws bf16 (K row-major, V transposed) ---
__global__ __launch_bounds__(256)
void prepass_kernel(const float* __restrict__ qkv,
                    short* __restrict__ kws, short* __restrict__ vtws)
{
    __shared__ float lds_t[64][65];

    const int tid = threadIdx.x;
    const int bh  = blockIdx.x >> 5;
    const int s0  = (blockIdx.x & 31) * 64;

    const float* qkv_bh = qkv + (size_t)(bh >> 4) * (S_LEN * SROW) + (bh & 15) * DHEAD;
    short* kws_bh = kws  + (size_t)bh * (S_LEN * DHEAD);
    short* vt_bh  = vtws + (size_t)bh * (S_LEN * DHEAD);

    const int row = tid >> 2;
    const int cq  = (tid & 3) * 16;

    {
        const float* kp = qkv_bh + (size_t)(s0 + row) * SROW + KOFF + cq;
        f32x4 a = *(const f32x4*)kp,       b = *(const f32x4*)(kp + 4);
        f32x4 c = *(const f32x4*)(kp + 8), d = *(const f32x4*)(kp + 12);
        bf16x8 w0, w1;
        #pragma unroll
        for (int j = 0; j < 4; ++j) {
            w0[j] = f2bf(a[j]); w0[4 + j] = f2bf(b[j]);
            w1[j] = f2bf(c[j]); w1[4 + j] = f2bf(d[j]);
        }
        *(bf16x8*)&kws_bh[(size_t)(s0 + row) * 64 + cq]     = w0;
        *(bf16x8*)&kws_bh[(size_t)(s0 + row) * 64 + cq + 8] = w1;
    }
    {
        const float* vp = qkv_bh + (size_t)(s0 + row) * SROW + VOFF + cq;
        f32x4 a = *(const f32x4*)vp,       b = *(const f32x4*)(vp + 4);
        f32x4 c = *(const f32x4*)(vp + 8), d = *(const f32x4*)(vp + 12);
        #pragma unroll
        for (int j = 0; j < 4; ++j) {
            lds_t[row][cq + j]      = a[j];
            lds_t[row][cq + 4 + j]  = b[j];
            lds_t[row][cq + 8 + j]  = c[j];
            lds_t[row][cq + 12 + j] = d[j];
        }
    }
    __syncthreads();
    {
        const int d = row, sq = cq;
        bf16x8 w0, w1;
        #pragma unroll
        for (int j = 0; j < 8; ++j) {
            w0[j] = f2bf(lds_t[sq + j][d]);
            w1[j] = f2bf(lds_t[sq + 8 + j][d]);
        }
        *(bf16x8*)&vt_bh[(size_t)d * S_LEN + s0 + sq]     = w0;
        *(bf16x8*)&vt_bh[(size_t)d * S_LEN + s0 + sq + 8] = w1;
    }
}

// ---------------- main kernel (8-wave chunk-per-wave, ~42 KB LDS) ------------
__global__ __launch_bounds__(512)
void attn_fwd_ws(const float* __restrict__ qkv,
                 const short* __restrict__ kws, const short* __restrict__ vtws,
                 float* __restrict__ out)
{
    __shared__ __attribute__((aligned(16))) short lds_k [KVBLK * 64];     // 8 KB (single)
    __shared__ __attribute__((aligned(16))) short lds_vt[2][DHEAD * 64];  // 16 KB (dbuf)
    __shared__ __attribute__((aligned(16))) short lds_p [8][16][PPIT];    // 18 KB

    const int tid  = threadIdx.x;
    const int wave = tid >> 6;           // 0..7
    const int lane = tid & 63;
    const int l16  = lane & 15;
    const int lg   = lane >> 4;
    const int lr8  = lane >> 3;          // 0..7
    const int lc8  = lane & 7;
    const int swz  = (lc8 * 8) ^ (lr8 << 3);   // DMA-source swizzle (shorts)
    const int rsw  = (l16 & 7) << 3;           // K/V read-side swizzle base

    const int bid = blockIdx.x;
    const int pr  = bid & 15;
    const int bh  = bid >> 4;

    const float* qkv_bh = qkv + (size_t)(bh >> 4) * (S_LEN * SROW) + (bh & 15) * DHEAD;
    const short* kws_bh = kws  + (size_t)bh * (S_LEN * DHEAD);
    const short* vt_bh  = vtws + (size_t)bh * (S_LEN * DHEAD);

    const int qbA = pr;
    const int qbB = NQB - 1 - pr;
    // wave -> chunk (0..3 -> A, 4..7 -> B), 16-row slice = (wave&3)*16
    const int qb   = (wave < 4) ? qbA : qbB;
    const int qlo  = qb * CHUNK + (wave & 3) * 16;

    // P bases (per wave)
    short* pwr = &lds_p[wave][lg * 4][l16];        // writer: + r*PPIT + c*16
    const short* prd = &lds_p[wave][l16][lg * 8];  // reader: + ks*32

    // staging row for this thread: 8 rows per wave, 64 rows per tile
    const int strow = wave * 8 + lr8;

    // ---- prologue: DMA K(0) and V(0) (one 16B shot each per thread) ----
    gl_lds16(&kws_bh[(size_t)strow * 64 + swz],    &lds_k    [wave * 512]);
    gl_lds16(&vt_bh [(size_t)strow * S_LEN + swz], &lds_vt[0][wave * 512]);

    // ---- Q fragments (pre-scaled by 0.125 * log2(e)) ----
    const float qscale = 0.125f * 1.44269504088896f;
    bf16x8 qf[2];
    #pragma unroll
    for (int ks = 0; ks < 2; ++ks) {
        const float* qp = qkv_bh + (size_t)(qlo + l16) * SROW + ks * 32 + lg * 8;
        f32x4 a = *(const f32x4*)qp;
        f32x4 c = *(const f32x4*)(qp + 4);
        bf16x8 v;
        #pragma unroll
        for (int j = 0; j < 4; ++j) { v[j] = f2bf(a[j] * qscale); v[4 + j] = f2bf(c[j] * qscale); }
        qf[ks] = v;
    }

    // ---- ones B-fragment for row-sum MFMA ----
    bf16x8 onesf;
    #pragma unroll
    for (int j = 0; j < 8; ++j) onesf[j] = (short)0x3F80;   // bf16 1.0

    // ---- flash state (verified D layout: q = qlo + lg*4 + r) ----
    f32x4 o[4];           // o[n][r] = O[q][d = n*16 + l16]
    f32x4 lsum;           // lsum[r]
    float m_r[4];         // running max (log2 domain)
    #pragma unroll
    for (int n = 0; n < 4; ++n) o[n] = (f32x4){0.f, 0.f, 0.f, 0.f};
    lsum = (f32x4){0.f, 0.f, 0.f, 0.f};
    #pragma unroll
    for (int r = 0; r < 4; ++r) m_r[r] = -1e30f;

    __syncthreads();   // tile 0 resident

    const int ntiles = qbB + 1;
    int cur = 0;

    for (int it = 0; it < ntiles; ++it) {
        const int kv0 = it * KVBLK;
        const bool act = (kv0 <= qlo + 15);   // wave-uniform activity

        // ---- S = Q K^T (K fully consumed here) ----
        f32x4 s[4];
        if (act) {
            #pragma unroll
            for (int c = 0; c < 4; ++c) s[c] = (f32x4){0.f, 0.f, 0.f, 0.f};
            #pragma unroll
            for (int ks = 0; ks < 2; ++ks) {
                #pragma unroll
                for (int c = 0; c < 4; ++c) {
                    bf16x8 kf = *(const bf16x8*)&lds_k[(c * 16 + l16) * 64 + ((ks * 32 + lg * 8) ^ rsw)];
                    s[c] = __builtin_amdgcn_mfma_f32_16x16x32_bf16(qf[ks], kf, s[c], 0, 0, 0);
                }
            }
        }

        __syncthreads();   // K consumed by all active waves -> safe to overwrite

        // ---- issue next tile's DMA (all waves; lands under softmax+PV) ----
        if (it + 1 < ntiles) {
            const int kn = kv0 + KVBLK;
            gl_lds16(&kws_bh[(size_t)(kn + strow) * 64 + swz],  &lds_k          [wave * 512]);
            gl_lds16(&vt_bh [(size_t)strow * S_LEN + kn + swz], &lds_vt[cur ^ 1][wave * 512]);
        }

        if (act) {
            // ---- causal mask (q = qlo + lg*4 + r, k = kv0 + c*16 + l16) ----
            if (kv0 + KVBLK - 1 > qlo) {
                #pragma unroll
                for (int r = 0; r < 4; ++r) {
                    const int qg = qlo + lg * 4 + r;
                    #pragma unroll
                    for (int c = 0; c < 4; ++c)
                        if (kv0 + c * 16 + l16 > qg) s[c][r] = -1e30f;
                }
            }

            // in-lane per-row max over c
            float lmax[4];
            #pragma unroll
            for (int r = 0; r < 4; ++r)
                lmax[r] = fmaxf(fmaxf(s[0][r], s[1][r]), fmaxf(s[2][r], s[3][r]));

            // defer-max vote (THR = 11.54 log2-units)
            const int okflag = (lmax[0] <= m_r[0] + 11.54f) && (lmax[1] <= m_r[1] + 11.54f) &&
                               (lmax[2] <= m_r[2] + 11.54f) && (lmax[3] <= m_r[3] + 11.54f);
            if (!__all(okflag)) {
                #pragma unroll
                for (int r = 0; r < 4; ++r) {
                    float mt = lmax[r];
                    mt = fmaxf(mt, __shfl_xor(mt, 1));
                    mt = fmaxf(mt, __shfl_xor(mt, 2));
                    mt = fmaxf(mt, __shfl_xor(mt, 4));
                    mt = fmaxf(mt, __shfl_xor(mt, 8));
                    const float mn    = fmaxf(m_r[r], mt);
                    const float alpha = fexp2(m_r[r] - mn);
                    m_r[r] = mn;
                    lsum[r] *= alpha;
                    #pragma unroll
                    for (int n = 0; n < 4; ++n) o[n][r] *= alpha;
                }
            }

            // P = 2^(S - m) -> identity-layout P rows (compile-time offsets)
            #pragma unroll
            for (int c = 0; c < 4; ++c) {
                #pragma unroll
                for (int r = 0; r < 4; ++r) {
                    const float p = fexp2(s[c][r] - m_r[r]);
                    pwr[r * PPIT + c * 16] = f2bf_trunc(p);
                }
            }
            // wave-local P visibility before cross-lane fragment reads
            asm volatile("s_waitcnt lgkmcnt(0)" ::: "memory");
            __builtin_amdgcn_sched_barrier(0);

            // ---- O += P V ; lsum += P · 1 ----
            __builtin_amdgcn_s_setprio(1);
            #pragma unroll
            for (int ks = 0; ks < 2; ++ks) {
                bf16x8 pa = *(const bf16x8*)&prd[ks * 32];
                lsum = __builtin_amdgcn_mfma_f32_16x16x32_bf16(pa, onesf, lsum, 0, 0, 0);
                #pragma unroll
                for (int n = 0; n < 4; ++n) {
                    bf16x8 vf = *(const bf16x8*)&lds_vt[cur][(n * 16 + l16) * 64 + ((ks * 32 + lg * 8) ^ rsw)];
                    o[n] = __builtin_amdgcn_mfma_f32_16x16x32_bf16(pa, vf, o[n], 0, 0, 0);
                }
            }
            __builtin_amdgcn_s_setprio(0);
        }
        __syncthreads();   // drains K/V DMA; PV done before next V overwrite
        cur ^= 1;
    }

    // ---- epilogue: out[q][d] = o[n][r] / lsum[r] ----
    float* outp = out + ((size_t)bh * S_LEN + qlo) * DHEAD;
    #pragma unroll
    for (int r = 0; r < 4; ++r) {
        const float inv = 1.0f / lsum[r];
        #pragma unroll
        for (int n = 0; n < 4; ++n)
            outp[(lg * 4 + r) * DHEAD + n * 16 + l16] = o[n][r] * inv;
    }
}

// ---------------- fallback (round-2 kernel, verified) ------------------------
#define KP 72
#define VP 72
#define PP 76
__global__ __launch_bounds__(256)
void attn_fwd_fallback(const float* __restrict__ qkv, float* __restrict__ out)
{
    __shared__ __attribute__((aligned(16))) short lds_k [KVBLK * KP];
    __shared__ __attribute__((aligned(16))) short lds_vt[DHEAD * VP];
    __shared__ __attribute__((aligned(16))) short lds_p [4 * 32 * PP];

    const int tid  = threadIdx.x;
    const int wave = tid >> 6;
    const int lane = tid & 63;
    const int l16  = lane & 15;
    const int lg   = lane >> 4;

    const int bid = blockIdx.x;
    const int pr  = bid & 15;
    const int bh  = bid >> 4;

    const float* qkv_bh = qkv + (size_t)(bh >> 4) * (S_LEN * SROW) + (bh & 15) * DHEAD;
    const int qbA = pr;
    const int qbB = NQB - 1 - pr;
    const int qloA = qbA * CHUNK + wave * 16;
    const int qloB = qbB * CHUNK + wave * 16;

    bf16x8 qf[2][2];
    #pragma unroll
    for (int m = 0; m < 2; ++m) {
        const int qrow = (m == 0 ? qloA : qloB) + l16;
        #pragma unroll
        for (int ks = 0; ks < 2; ++ks) {
            const float* qp = qkv_bh + (size_t)qrow * SROW + ks * 32 + lg * 8;
            f32x4 a = *(const f32x4*)qp;
            f32x4 c = *(const f32x4*)(qp + 4);
            bf16x8 v;
            #pragma unroll
            for (int j = 0; j < 4; ++j) { v[j] = f2bf(a[j] * 0.125f); v[4 + j] = f2bf(c[j] * 0.125f); }
            qf[m][ks] = v;
        }
    }

    f32x4 o[2][4];
    float m_r[2][4], l_r[2][4];
    #pragma unroll
    for (int m = 0; m < 2; ++m)
        #pragma unroll
        for (int n = 0; n < 4; ++n) o[m][n] = (f32x4){0.f, 0.f, 0.f, 0.f};
    #pragma unroll
    for (int m = 0; m < 2; ++m)
        #pragma unroll
        for (int r = 0; r < 4; ++r) { m_r[m][r] = -1e30f; l_r[m][r] = 0.f; }

    const int st_kr = tid >> 2;
    const int st_kc = (tid & 3) * 16;
    const int st_vp = tid & 31;
    const int st_vd = (tid >> 5) * 8;

    f32x4 pk[4], pv[4];
    const int ntiles = qbB + 1;
    {
        const float* kp = qkv_bh + (size_t)st_kr * SROW + KOFF + st_kc;
        pk[0] = *(const f32x4*)kp;       pk[1] = *(const f32x4*)(kp + 4);
        pk[2] = *(const f32x4*)(kp + 8); pk[3] = *(const f32x4*)(kp + 12);
        const float* vp = qkv_bh + (size_t)(2 * st_vp) * SROW + VOFF + st_vd;
        pv[0] = *(const f32x4*)vp;           pv[1] = *(const f32x4*)(vp + 4);
        pv[2] = *(const f32x4*)(vp + SROW);  pv[3] = *(const f32x4*)(vp + SROW + 4);
    }

    for (int it = 0; it < ntiles; ++it) {
        const int kv0 = it * KVBLK;
        {
            bf16x8 w0, w1;
            #pragma unroll
            for (int j = 0; j < 4; ++j) {
                w0[j] = f2bf(pk[0][j]); w0[4 + j] = f2bf(pk[1][j]);
                w1[j] = f2bf(pk[2][j]); w1[4 + j] = f2bf(pk[3][j]);
            }
            *(bf16x8*)&lds_k[st_kr * KP + st_kc]     = w0;
            *(bf16x8*)&lds_k[st_kr * KP + st_kc + 8] = w1;
            #pragma unroll
            for (int i = 0; i < 4; ++i) {
                *(unsigned int*)&lds_vt[(st_vd + i)     * VP + 2 * st_vp] = pack2(pv[0][i], pv[2][i]);
                *(unsigned int*)&lds_vt[(st_vd + 4 + i) * VP + 2 * st_vp] = pack2(pv[1][i], pv[3][i]);
            }
        }
        __syncthreads();
        if (it + 1 < ntiles) {
            const int kn = kv0 + KVBLK;
            const float* kp = qkv_bh + (size_t)(kn + st_kr) * SROW + KOFF + st_kc;
            pk[0] = *(const f32x4*)kp;       pk[1] = *(const f32x4*)(kp + 4);
            pk[2] = *(const f32x4*)(kp + 8); pk[3] = *(const f32x4*)(kp + 12);
            const float* vp = qkv_bh + (size_t)(kn + 2 * st_vp) * SROW + VOFF + st_vd;
            pv[0] = *(const f32x4*)vp;           pv[1] = *(const f32x4*)(vp + 4);
            pv[2] = *(const f32x4*)(vp + SROW);  pv[3] = *(const f32x4*)(vp + SROW + 4);
        }
        const bool actA = (kv0 <= qloA + 15);
        f32x4 s[2][4];
        #pragma unroll
        for (int m = 0; m < 2; ++m)
            #pragma unroll
            for (int c = 0; c < 4; ++c) s[m][c] = (f32x4){0.f, 0.f, 0.f, 0.f};
        #pragma unroll
        for (int ks = 0; ks < 2; ++ks) {
            #pragma unroll
            for (int c = 0; c < 4; ++c) {
                bf16x8 kf = *(const bf16x8*)&lds_k[(c * 16 + l16) * KP + ks * 32 + lg * 8];
                s[1][c] = __builtin_amdgcn_mfma_f32_16x16x32_bf16(qf[1][ks], kf, s[1][c], 0, 0, 0);
                if (actA)
                    s[0][c] = __builtin_amdgcn_mfma_f32_16x16x32_bf16(qf[0][ks], kf, s[0][c], 0, 0, 0);
            }
        }
        short* pw = &lds_p[wave * 32 * PP];
        #pragma unroll
        for (int m = 0; m < 2; ++m) {
            if (m == 0 && !actA) continue;
            const int qlo_m = (m == 0) ? qloA : qloB;
            if (kv0 + KVBLK - 1 > qlo_m) {
                #pragma unroll
                for (int r = 0; r < 4; ++r) {
                    const int qg = qlo_m + lg * 4 + r;
                    #pragma unroll
                    for (int c = 0; c < 4; ++c)
                        if (kv0 + c * 16 + l16 > qg) s[m][c][r] = -1e30f;
                }
            }
            #pragma unroll
            for (int r = 0; r < 4; ++r) {
                float mt = fmaxf(fmaxf(s[m][0][r], s[m][1][r]), fmaxf(s[m][2][r], s[m][3][r]));
                mt = fmaxf(mt, __shfl_xor(mt, 1));
                mt = fmaxf(mt, __shfl_xor(mt, 2));
                mt = fmaxf(mt, __shfl_xor(mt, 4));
                mt = fmaxf(mt, __shfl_xor(mt, 8));
                const float mn    = fmaxf(m_r[m][r], mt);
                const float alpha = __expf(m_r[m][r] - mn);
                m_r[m][r] = mn;
                float p0 = __expf(s[m][0][r] - mn);
                float p1 = __expf(s[m][1][r] - mn);
                float p2 = __expf(s[m][2][r] - mn);
                float p3 = __expf(s[m][3][r] - mn);
                float rs = (p0 + p1) + (p2 + p3);
                rs += __shfl_xor(rs, 1);
                rs += __shfl_xor(rs, 2);
                rs += __shfl_xor(rs, 4);
                rs += __shfl_xor(rs, 8);
                l_r[m][r] = l_r[m][r] * alpha + rs;
                #pragma unroll
                for (int n = 0; n < 4; ++n) o[m][n][r] *= alpha;
                const int prow = m * 16 + lg * 4 + r;
                pw[prow * PP +      l16] = f2bf(p0);
                pw[prow * PP + 16 + l16] = f2bf(p1);
                pw[prow * PP + 32 + l16] = f2bf(p2);
                pw[prow * PP + 48 + l16] = f2bf(p3);
            }
        }
        asm volatile("s_waitcnt lgkmcnt(0)" ::: "memory");
        __builtin_amdgcn_sched_barrier(0);
        #pragma unroll
        for (int ks = 0; ks < 2; ++ks) {
            bf16x8 pa1 = *(const bf16x8*)&pw[(16 + l16) * PP + ks * 32 + lg * 8];
            #pragma unroll
            for (int n = 0; n < 4; ++n) {
                bf16x8 vf = *(const bf16x8*)&lds_vt[(n * 16 + l16) * VP + ks * 32 + lg * 8];
                o[1][n] = __builtin_amdgcn_mfma_f32_16x16x32_bf16(pa1, vf, o[1][n], 0, 0, 0);
            }
            if (actA) {
                bf16x8 pa0 = *(const bf16x8*)&pw[l16 * PP + ks * 32 + lg * 8];
                #pragma unroll
                for (int n = 0; n < 4; ++n) {
                    bf16x8 vf = *(const bf16x8*)&lds_vt[(n * 16 + l16) * VP + ks * 32 + lg * 8];
                    o[0][n] = __builtin_amdgcn_mfma_f32_16x16x32_bf16(pa0, vf, o[0][n], 0, 0, 0);
                }
            }
        }
        __syncthreads();
    }
    #pragma unroll
    for (int m = 0; m < 2; ++m) {
        const int qlo_m = (m == 0) ? qloA : qloB;
        float* outp = out + ((size_t)bh * S_LEN + qlo_m) * DHEAD;
        #pragma unroll
        for (int r = 0; r < 4; ++r) {
            const float inv = 1.0f / l_r[m][r];
            #pragma unroll
            for (int n = 0; n < 4; ++n)
                outp[(lg * 4 + r) * DHEAD + n * 16 + l16] = o[m][n][r] * inv;
        }
    }
}

extern "C" void kernel_launch(void* const* d_in, const int* in_sizes, int n_in,
                              void* d_out, int out_size, void* d_ws, size_t ws_size,
                              hipStream_t stream) {
    const float* qkv = (const float*)d_in[0];
    float* out = (float*)d_out;
    const size_t need = (size_t)2 * 64 * S_LEN * DHEAD * sizeof(short);  // 33.55 MB
    const int nblocks = NPAIR * 4 * NHEAD;   // 1024
    if (ws_size >= need) {
        short* kws  = (short*)d_ws;
        short* vtws = kws + (size_t)64 * S_LEN * DHEAD;
        prepass_kernel<<<dim3(64 * 32), dim3(256), 0, stream>>>(qkv, kws, vtws);
        attn_fwd_ws<<<dim3(nblocks), dim3(512), 0, stream>>>(qkv, kws, vtws, out);
    } else {
        attn_fwd_fallback<<<dim3(nblocks), dim3(256), 0, stream>>>(qkv, out);
    }
}